// Round 4
// baseline (1806.264 us; speedup 1.0000x reference)
//
#include <hip/hip_runtime.h>
#include <cstdint>
#include <cstddef>

typedef unsigned short u16;
typedef __bf16 bf16x8 __attribute__((ext_vector_type(8)));
typedef float f32x4 __attribute__((ext_vector_type(4)));
typedef unsigned short u16x8 __attribute__((ext_vector_type(8)));
typedef unsigned short u16x4 __attribute__((ext_vector_type(4)));

__device__ __forceinline__ u16 f2bf(float f) {
  union { float f; unsigned u; } x; x.f = f;
  unsigned r = x.u + 0x7fffu + ((x.u >> 16) & 1u);   // RNE
  return (u16)(r >> 16);
}
__device__ __forceinline__ float bf2f(u16 u) {
  union { unsigned u; float f; } x; x.u = ((unsigned)u) << 16;
  return x.f;
}
// async global->LDS, 16B per lane; LDS dest is wave-uniform base + lane*16
__device__ __forceinline__ void gload16(const void* g, void* l) {
  __builtin_amdgcn_global_load_lds(
      (const __attribute__((address_space(1))) unsigned int*)g,
      (__attribute__((address_space(3))) unsigned int*)l, 16, 0, 0);
}

// ---------------------------------------------------------------------------
// GEMM: C = A[.][K](lda) @ Bt^T + bias. Bt[N][K] bf16. 128x128 tile, BK=32,
// 4 waves (2x2 of 64x64), mfma_f32_16x16x32_bf16. 1-D grid, col-fastest +
// bijective XCD chunking (nwg%8==0). A bf16 (global_load_lds) or fp32 (VALU).
// ---------------------------------------------------------------------------
template<int A_F32, int OUT_BF16, int RELU>
__global__ __launch_bounds__(256) void gemm_bt(
    const void* __restrict__ Ap, int lda, const u16* __restrict__ Bt,
    const float* __restrict__ bias, void* __restrict__ Cp,
    int N, int K, int gy)
{
  __shared__ u16 As[128][32];
  __shared__ u16 Bs[128][32];
  const int tid  = threadIdx.x;
  const int lane = tid & 63, w = tid >> 6;
  const int nwg = gridDim.x, o = blockIdx.x;
  const int lid = (o & 7) * (nwg >> 3) + (o >> 3);   // contiguous lid -> same XCD
  const int by = lid % gy, bx = lid / gy;
  const int row0 = bx * 128, col0 = by * 128;
  const int wr = (w >> 1) * 64, wc = (w & 1) * 64;
  const int fr = lane & 15, fg = lane >> 4;          // fragment row / k-group
  const int grow  = (w << 5) + (lane >> 2);          // gload: wave w -> rows w*32..
  const int gcolB = (lane & 3) << 4;

  f32x4 acc[4][4] = {};

  for (int k0 = 0; k0 < K; k0 += 32) {
    if (A_F32) {
      const float* A = (const float*)Ap;
      const int ar = tid >> 3, ak = (tid & 7) << 2;
      #pragma unroll
      for (int p = 0; p < 4; ++p) {
        f32x4 v = *(const f32x4*)&A[(size_t)(row0 + ar + 32*p) * lda + k0 + ak];
        u16x4 q = { f2bf(v[0]), f2bf(v[1]), f2bf(v[2]), f2bf(v[3]) };
        *(u16x4*)&As[ar + 32*p][ak] = q;
      }
    } else {
      const char* A = (const char*)Ap;
      #pragma unroll
      for (int h = 0; h < 2; ++h)
        gload16(A + ((size_t)(row0 + grow + h*16) * lda + k0) * 2 + gcolB,
                &As[(w << 5) + h*16][0]);
    }
    {
      const char* B = (const char*)Bt;
      #pragma unroll
      for (int h = 0; h < 2; ++h)
        gload16(B + ((size_t)(col0 + grow + h*16) * K + k0) * 2 + gcolB,
                &Bs[(w << 5) + h*16][0]);
    }
    __syncthreads();
    bf16x8 af[4], bfr[4];
    #pragma unroll
    for (int i = 0; i < 4; ++i) af[i]  = *(const bf16x8*)&As[wr + i*16 + fr][fg*8];
    #pragma unroll
    for (int j = 0; j < 4; ++j) bfr[j] = *(const bf16x8*)&Bs[wc + j*16 + fr][fg*8];
    #pragma unroll
    for (int i = 0; i < 4; ++i)
      #pragma unroll
      for (int j = 0; j < 4; ++j)
        acc[i][j] = __builtin_amdgcn_mfma_f32_16x16x32_bf16(af[i], bfr[j], acc[i][j], 0, 0, 0);
    __syncthreads();
  }

  #pragma unroll
  for (int j = 0; j < 4; ++j) {
    const int c  = col0 + wc + j*16 + fr;
    const float bv = bias[c];
    #pragma unroll
    for (int i = 0; i < 4; ++i) {
      #pragma unroll
      for (int t = 0; t < 4; ++t) {
        const int r = row0 + wr + i*16 + fg*4 + t;
        float v = acc[i][j][t] + bv;
        if (RELU) v = v > 0.f ? v : 0.f;
        if (OUT_BF16) ((u16*)Cp)[(size_t)r * N + c] = f2bf(v);
        else          ((float*)Cp)[(size_t)r * N + c] = v;
      }
    }
  }
}

// ---------------------------------------------------------------------------
// GEMM (N=256 fixed) + bias + residual + LayerNorm fused in epilogue.
// Tile 64 rows x 256 cols (full LN row per block); 4 waves as 64-col strips.
// A bf16 [.][K](lda); Res bf16 [.][256]; Y bf16 or fp32.
// ---------------------------------------------------------------------------
template<int OUT_BF16>
__global__ __launch_bounds__(256) void gemm_ln(
    const u16* __restrict__ Ap, int lda, const u16* __restrict__ Bt,
    const float* __restrict__ bias, const u16* __restrict__ Res,
    const float* __restrict__ g, const float* __restrict__ be,
    void* __restrict__ Y, int K)
{
  __shared__ u16 As[64][32];          // 4 KiB
  __shared__ u16 Bs[256][32];         // 16 KiB
  __shared__ float2 red[64][4];       // per-wave row partials (sum, sumsq)
  __shared__ float2 stats[64];        // per-row (mean, rstd)
  const int tid  = threadIdx.x;
  const int lane = tid & 63, w = tid >> 6;
  const int row0 = blockIdx.x * 64;
  const int wc = w * 64;
  const int fr = lane & 15, fg = lane >> 4;
  const int lrow = lane >> 2, lcolB = (lane & 3) << 4;

  f32x4 acc[4][4] = {};

  for (int k0 = 0; k0 < K; k0 += 32) {
    // A: 64 rows; wave w stages rows w*16..w*16+15 (one issue)
    gload16((const char*)Ap + ((size_t)(row0 + (w << 4) + lrow) * lda + k0) * 2 + lcolB,
            &As[w << 4][0]);
    // B: 256 rows; wave w stages rows w*64..w*64+63 (four issues)
    #pragma unroll
    for (int h = 0; h < 4; ++h)
      gload16((const char*)Bt + ((size_t)((w << 6) + h*16 + lrow) * K + k0) * 2 + lcolB,
              &Bs[(w << 6) + h*16][0]);
    __syncthreads();
    bf16x8 af[4], bfr[4];
    #pragma unroll
    for (int i = 0; i < 4; ++i) af[i]  = *(const bf16x8*)&As[i*16 + fr][fg*8];
    #pragma unroll
    for (int j = 0; j < 4; ++j) bfr[j] = *(const bf16x8*)&Bs[wc + j*16 + fr][fg*8];
    #pragma unroll
    for (int i = 0; i < 4; ++i)
      #pragma unroll
      for (int j = 0; j < 4; ++j)
        acc[i][j] = __builtin_amdgcn_mfma_f32_16x16x32_bf16(af[i], bfr[j], acc[i][j], 0, 0, 0);
    __syncthreads();
  }

  // v = acc + bias + residual; per-row partial sums within this wave's strip
  float ps[4][4] = {}, pq[4][4] = {};
  #pragma unroll
  for (int i = 0; i < 4; ++i) {
    #pragma unroll
    for (int t = 0; t < 4; ++t) {
      const int r = row0 + i*16 + fg*4 + t;
      #pragma unroll
      for (int j = 0; j < 4; ++j) {
        const int c = wc + j*16 + fr;
        float v = acc[i][j][t] + bias[c] + bf2f(Res[(size_t)r * 256 + c]);
        acc[i][j][t] = v;
        ps[i][t] += v;
        pq[i][t] += v * v;
      }
    }
  }
  #pragma unroll
  for (int d = 1; d < 16; d <<= 1) {
    #pragma unroll
    for (int i = 0; i < 4; ++i)
      #pragma unroll
      for (int t = 0; t < 4; ++t) {
        ps[i][t] += __shfl_xor(ps[i][t], d, 64);
        pq[i][t] += __shfl_xor(pq[i][t], d, 64);
      }
  }
  if (fr == 0) {
    #pragma unroll
    for (int i = 0; i < 4; ++i)
      #pragma unroll
      for (int t = 0; t < 4; ++t)
        red[i*16 + fg*4 + t][w] = make_float2(ps[i][t], pq[i][t]);
  }
  __syncthreads();
  if (tid < 64) {
    float S = 0.f, Q = 0.f;
    #pragma unroll
    for (int ww = 0; ww < 4; ++ww) { float2 p = red[tid][ww]; S += p.x; Q += p.y; }
    const float m = S * (1.f/256.f);
    const float var = Q * (1.f/256.f) - m*m;
    stats[tid] = make_float2(m, rsqrtf(var + 1e-5f));
  }
  __syncthreads();
  #pragma unroll
  for (int i = 0; i < 4; ++i) {
    #pragma unroll
    for (int t = 0; t < 4; ++t) {
      const int rl = i*16 + fg*4 + t;
      const float2 st = stats[rl];
      const size_t r = row0 + rl;
      #pragma unroll
      for (int j = 0; j < 4; ++j) {
        const int c = wc + j*16 + fr;
        const float y = (acc[i][j][t] - st.x) * st.y * g[c] + be[c];
        if (OUT_BF16) ((u16*)Y)[r * 256 + c] = f2bf(y);
        else          ((float*)Y)[r * 256 + c] = y;
      }
    }
  }
}

// ---------------------------------------------------------------------------
// Windowed attention, strided I/O: one block per window; 8 heads x 32 q-rows.
// Each thread owns one (head, q) row. Q read direct global->reg (only owner
// reads it); K/V staged in LDS. O may alias Q/K/V (window-local, per-thread
// read-before-write on the Q row; K/V consumed from LDS after barrier).
// ---------------------------------------------------------------------------
__global__ __launch_bounds__(256) void attn_win(
    const u16* Q, int sq, const u16* __restrict__ K, int sk,
    const u16* __restrict__ V, int sv, u16* O, int so)
{
  __shared__ u16 Ks[32][256];
  __shared__ u16 Vs[32][256];
  const int tid = threadIdx.x;
  const size_t w0 = (size_t)blockIdx.x * 32;
  const int h = tid >> 5, q = tid & 31;
  const int co = h << 5;

  float qr[32];
  #pragma unroll
  for (int d8 = 0; d8 < 4; ++d8) {
    u16x8 v = *(const u16x8*)&Q[(w0 + q) * sq + co + d8*8];
    #pragma unroll
    for (int j2 = 0; j2 < 8; ++j2) qr[d8*8 + j2] = bf2f(v[j2]);
  }
  #pragma unroll
  for (int p = 0; p < 4; ++p) {
    const int c = tid + p * 256;
    const int r = c >> 5, cc = (c & 31) << 3;
    *(u16x8*)&Ks[r][cc] = *(const u16x8*)&K[(w0 + r) * sk + cc];
    *(u16x8*)&Vs[r][cc] = *(const u16x8*)&V[(w0 + r) * sv + cc];
  }
  __syncthreads();

  float s[32];
  float mx = -1e30f;
  const float scale = 0.17677669529663687f;   // 1/sqrt(32)
  #pragma unroll
  for (int k = 0; k < 32; ++k) {
    float a = 0.f;
    #pragma unroll
    for (int d8 = 0; d8 < 4; ++d8) {
      u16x8 v = *(const u16x8*)&Ks[k][co + d8*8];
      #pragma unroll
      for (int j2 = 0; j2 < 8; ++j2) a += qr[d8*8 + j2] * bf2f(v[j2]);
    }
    a *= scale;
    s[k] = a;
    mx = fmaxf(mx, a);
  }
  float sum = 0.f;
  #pragma unroll
  for (int k = 0; k < 32; ++k) { float e = __expf(s[k] - mx); s[k] = e; sum += e; }
  const float inv = 1.f / sum;

  float oa[32];
  #pragma unroll
  for (int d = 0; d < 32; ++d) oa[d] = 0.f;
  #pragma unroll
  for (int k = 0; k < 32; ++k) {
    const float p = s[k];
    #pragma unroll
    for (int d8 = 0; d8 < 4; ++d8) {
      u16x8 v = *(const u16x8*)&Vs[k][co + d8*8];
      #pragma unroll
      for (int j2 = 0; j2 < 8; ++j2) oa[d8*8 + j2] += p * bf2f(v[j2]);
    }
  }
  #pragma unroll
  for (int d8 = 0; d8 < 4; ++d8) {
    u16x8 ov;
    #pragma unroll
    for (int j2 = 0; j2 < 8; ++j2) ov[j2] = f2bf(oa[d8*8 + j2] * inv);
    *(u16x8*)&O[(w0 + q) * so + co + d8*8] = ov;
  }
}

// ---------------------------------------------------------------------------
__global__ __launch_bounds__(256) void wprep(
    const float* __restrict__ W, u16* __restrict__ Wt, int K, int N)
{
  const int idx = blockIdx.x * 256 + threadIdx.x;
  if (idx >= K * N) return;
  const int k = idx / N, n = idx - k * N;
  Wt[(size_t)n * K + k] = f2bf(W[idx]);
}

__global__ __launch_bounds__(256) void bcat(
    const float* __restrict__ a, const float* __restrict__ b,
    const float* __restrict__ c, float* __restrict__ o)
{
  const int i = blockIdx.x * 256 + threadIdx.x;
  o[i] = i < 256 ? a[i] : (i < 512 ? b[i - 256] : c[i - 512]);
}

__global__ __launch_bounds__(256) void f32_to_bf16(
    const float* __restrict__ X, u16* __restrict__ Y)
{
  const size_t i = ((size_t)blockIdx.x * 256 + threadIdx.x) * 8;
  f32x4 a = *(const f32x4*)&X[i];
  f32x4 b = *(const f32x4*)&X[i + 4];
  u16x8 o = { f2bf(a[0]), f2bf(a[1]), f2bf(a[2]), f2bf(a[3]),
              f2bf(b[0]), f2bf(b[1]), f2bf(b[2]), f2bf(b[3]) };
  *(u16x8*)&Y[i] = o;
}

// ---------------------------------------------------------------------------
extern "C" void kernel_launch(void* const* d_in, const int* in_sizes, int n_in,
                              void* d_out, int out_size, void* d_ws, size_t ws_size,
                              hipStream_t stream)
{
  const float* query  = (const float*)d_in[0];
  const float* keyval = (const float*)d_in[1];
  const float* Wq = (const float*)d_in[2];  const float* bq  = (const float*)d_in[3];
  const float* Wk = (const float*)d_in[4];  const float* bk  = (const float*)d_in[5];
  const float* Wv = (const float*)d_in[6];  const float* bv  = (const float*)d_in[7];
  const float* Wo = (const float*)d_in[8];  const float* bo  = (const float*)d_in[9];
  const float* g1 = (const float*)d_in[10]; const float* be1 = (const float*)d_in[11];
  const float* W1 = (const float*)d_in[12]; const float* bf1 = (const float*)d_in[13];
  const float* W2 = (const float*)d_in[14]; const float* bf2 = (const float*)d_in[15];
  const float* g2 = (const float*)d_in[16]; const float* be2 = (const float*)d_in[17];

  const int M  = 131072;     // B*L token rows
  const int MC = 32768;      // row chunk (window-aligned), 4 chunks
  char* ws = (char*)d_ws;
  // Workspace (<=194 MiB of the 512 MiB d_ws):
  //   [0,64MiB)    : xcur bf16 [M][256]
  //   [64,128MiB)  : x1   bf16 [M][256]
  //   [128,192MiB) : per-chunk work: Qc/KVc or QKVc or Hc
  //   [192MiB,..)  : bf16 weights + fused qkv bias
  u16*  xcur = (u16*)ws;
  u16*  x1   = (u16*)(ws + (64ull  << 20));
  char* work =        ws + (128ull << 20);
  u16*  Qc   = (u16*)work;
  u16*  KVc  = (u16*)(work + (16ull << 20));
  u16*  QKVc = (u16*)work;
  u16*  Hc   = (u16*)work;
  u16*  WqkvT = (u16*)(ws + (192ull << 20));   // [768][256]
  u16*  WoT   = WqkvT + 196608;                // [256][256]
  u16*  W1T   = WoT   + 65536;                 // [1024][256]
  u16*  W2T   = W1T   + 262144;                // [256][1024]
  float* bqkv = (float*)(W2T + 262144);        // [768]

  wprep<<<256,  256, 0, stream>>>(Wq, WqkvT,          256, 256);
  wprep<<<256,  256, 0, stream>>>(Wk, WqkvT +  65536, 256, 256);
  wprep<<<256,  256, 0, stream>>>(Wv, WqkvT + 131072, 256, 256);
  wprep<<<256,  256, 0, stream>>>(Wo, WoT, 256, 256);
  wprep<<<1024, 256, 0, stream>>>(W1, W1T, 256, 1024);
  wprep<<<1024, 256, 0, stream>>>(W2, W2T, 1024, 256);
  bcat<<<3, 256, 0, stream>>>(bq, bk, bv, bqkv);
  f32_to_bf16<<<16384, 256, 0, stream>>>(query, xcur);

  // NOTE: jnp.roll(x, -16, axis=1) permutes whole windows; the encoder layer is
  // window-local and position-independent, so roll + layer + unroll == layer.
  // Both rolls are elided (bit-exact equivalence).
  auto run_layer = [&](const float* kv_f32, int last) {
    for (int c = 0; c < 4; ++c) {
      const size_t ro = (size_t)c * MC;
      if (kv_f32) {   // layer 1: Q from xcur; fused K|V from fp32 keyval
        gemm_bt<0,1,0><<< 512, 256, 0, stream>>>(
            xcur + ro * 256, 256, WqkvT, bqkv, Qc, 256, 256, 2);
        gemm_bt<1,1,0><<<1024, 256, 0, stream>>>(
            kv_f32 + ro * 256, 256, WqkvT + 65536, bqkv + 256, KVc, 512, 256, 4);
        attn_win<<<1024, 256, 0, stream>>>(Qc, 256, KVc, 512, KVc + 256, 512, Qc, 256);
        gemm_ln<1><<<512, 256, 0, stream>>>(
            Qc, 256, WoT, bo, xcur + ro * 256, g1, be1, x1 + ro * 256, 256);
      } else {        // layer 2: fused Q|K|V from xcur
        gemm_bt<0,1,0><<<1536, 256, 0, stream>>>(
            xcur + ro * 256, 256, WqkvT, bqkv, QKVc, 768, 256, 6);
        attn_win<<<1024, 256, 0, stream>>>(
            QKVc, 768, QKVc + 256, 768, QKVc + 512, 768, QKVc, 768);
        gemm_ln<1><<<512, 256, 0, stream>>>(
            QKVc, 768, WoT, bo, xcur + ro * 256, g1, be1, x1 + ro * 256, 256);
      }
    }
    for (int c = 0; c < 4; ++c) {
      const size_t ro = (size_t)c * MC;
      gemm_bt<0,1,1><<<2048, 256, 0, stream>>>(
          x1 + ro * 256, 256, W1T, bf1, Hc, 1024, 256, 8);
      if (last)
        gemm_ln<0><<<512, 256, 0, stream>>>(
            Hc, 1024, W2T, bf2, x1 + ro * 256, g2, be2,
            (float*)d_out + ro * 256, 1024);
      else
        gemm_ln<1><<<512, 256, 0, stream>>>(
            Hc, 1024, W2T, bf2, x1 + ro * 256, g2, be2,
            xcur + ro * 256, 1024);
    }
  };

  run_layer(keyval, 0);    // layer 1: q = bf16(query), kv = keyval fp32
  run_layer(nullptr, 1);   // layer 2: q = kv = xcur; final LN -> d_out
}

// Round 5
// 1606.520 us; speedup vs baseline: 1.1243x; 1.1243x over previous
//
#include <hip/hip_runtime.h>
#include <cstdint>
#include <cstddef>

typedef unsigned short u16;
typedef __bf16 bf16x8 __attribute__((ext_vector_type(8)));
typedef float f32x4 __attribute__((ext_vector_type(4)));
typedef unsigned short u16x8 __attribute__((ext_vector_type(8)));
typedef unsigned short u16x4 __attribute__((ext_vector_type(4)));

__device__ __forceinline__ u16 f2bf(float f) {
  union { float f; unsigned u; } x; x.f = f;
  unsigned r = x.u + 0x7fffu + ((x.u >> 16) & 1u);   // RNE
  return (u16)(r >> 16);
}
__device__ __forceinline__ float bf2f(u16 u) {
  union { unsigned u; float f; } x; x.u = ((unsigned)u) << 16;
  return x.f;
}
// async global->LDS, 16B/lane; LDS dest = wave-uniform base + lane*16 (linear)
__device__ __forceinline__ void gload16(const void* g, void* l) {
  __builtin_amdgcn_global_load_lds(
      (const __attribute__((address_space(1))) unsigned int*)g,
      (__attribute__((address_space(3))) unsigned int*)l, 16, 0, 0);
}

// ---------------------------------------------------------------------------
// GEMM: C = A[.][K](lda) @ Bt^T + bias. A,Bt bf16; Bt[N][K]. 128x128 tile,
// BK=64, 4 waves (2x2 of 64x64), mfma_f32_16x16x32_bf16.
// LDS rows are 128B (8 slots of 16B). T2 both-sides swizzle: staging
// pre-swizzles the GLOBAL source slot (slot^row&7) while global_load_lds
// writes linearly; ds_read applies the same XOR -> 2-way conflicts only.
// 1-D grid, col-fastest decomposition + bijective XCD chunking (nwg%8==0).
// ---------------------------------------------------------------------------
template<int OUT_BF16, int RELU>
__global__ __launch_bounds__(256) void gemm_bt(
    const u16* __restrict__ Ap, int lda, const u16* __restrict__ Bt,
    const float* __restrict__ bias, void* __restrict__ Cp,
    int N, int K, int gy)
{
  __shared__ u16 As[128 * 64];
  __shared__ u16 Bs[128 * 64];
  const int tid  = threadIdx.x;
  const int lane = tid & 63, w = tid >> 6;
  const int nwg = gridDim.x, o = blockIdx.x;
  const int lid = (o & 7) * (nwg >> 3) + (o >> 3);   // contiguous lid -> same XCD
  const int by = lid % gy, bx = lid / gy;
  const int row0 = bx * 128, col0 = by * 128;
  const int wr = (w >> 1) * 64, wc = (w & 1) * 64;
  const int fr = lane & 15, fg = lane >> 4;          // fragment row / k-group
  // staging: wave w stages rows [w*32, w*32+32), 4 issues x 8 rows; lane l
  // covers row +(l>>3), slot l&7; source slot XOR-preswizzled by row&7=l>>3.
  const int srow  = (w << 5) + (lane >> 3);
  const int sslot = (lane & 7) ^ (lane >> 3);

  f32x4 acc[4][4] = {};

  for (int k0 = 0; k0 < K; k0 += 64) {
    #pragma unroll
    for (int h = 0; h < 4; ++h)
      gload16((const char*)Ap + ((size_t)(row0 + srow + h*8) * lda + k0) * 2 + sslot*16,
              &As[((w << 5) + h*8) * 64]);
    #pragma unroll
    for (int h = 0; h < 4; ++h)
      gload16((const char*)Bt + ((size_t)(col0 + srow + h*8) * K + k0) * 2 + sslot*16,
              &Bs[((w << 5) + h*8) * 64]);
    __syncthreads();
    #pragma unroll
    for (int kh = 0; kh < 2; ++kh) {
      bf16x8 af[4], bf[4];
      #pragma unroll
      for (int i = 0; i < 4; ++i) {
        const int r = wr + i*16 + fr;
        af[i] = *(const bf16x8*)&As[r*64 + ((((kh << 2) | fg) ^ (fr & 7)) << 3)];
      }
      #pragma unroll
      for (int j = 0; j < 4; ++j) {
        const int r = wc + j*16 + fr;
        bf[j] = *(const bf16x8*)&Bs[r*64 + ((((kh << 2) | fg) ^ (fr & 7)) << 3)];
      }
      #pragma unroll
      for (int i = 0; i < 4; ++i)
        #pragma unroll
        for (int j = 0; j < 4; ++j)
          acc[i][j] = __builtin_amdgcn_mfma_f32_16x16x32_bf16(af[i], bf[j], acc[i][j], 0, 0, 0);
    }
    __syncthreads();
  }

  // epilogue: D[row=fg*4+t][col=fr] per 16x16 fragment (m89-verified mapping)
  #pragma unroll
  for (int j = 0; j < 4; ++j) {
    const int c  = col0 + wc + j*16 + fr;
    const float bv = bias[c];
    #pragma unroll
    for (int i = 0; i < 4; ++i) {
      #pragma unroll
      for (int t = 0; t < 4; ++t) {
        const int r = row0 + wr + i*16 + fg*4 + t;
        float v = acc[i][j][t] + bv;
        if (RELU) v = v > 0.f ? v : 0.f;
        if (OUT_BF16) ((u16*)Cp)[(size_t)r * N + c] = f2bf(v);
        else          ((float*)Cp)[(size_t)r * N + c] = v;
      }
    }
  }
}

// ---------------------------------------------------------------------------
// Windowed attention, strided I/O: one block per window; 8 heads x 32 q-rows.
// Each thread owns one (head, q) row; K/V staged in LDS; Q direct to regs.
// O may alias Q/K/V (window-local; K/V consumed from LDS after barrier,
// Q row read by its owner thread before that thread's store).
// ---------------------------------------------------------------------------
__global__ __launch_bounds__(256) void attn_win(
    const u16* Q, int sq, const u16* __restrict__ K, int sk,
    const u16* __restrict__ V, int sv, u16* O, int so)
{
  __shared__ u16 Ks[32][256];
  __shared__ u16 Vs[32][256];
  const int tid = threadIdx.x;
  const size_t w0 = (size_t)blockIdx.x * 32;
  const int h = tid >> 5, q = tid & 31;
  const int co = h << 5;

  float qr[32];
  #pragma unroll
  for (int d8 = 0; d8 < 4; ++d8) {
    u16x8 v = *(const u16x8*)&Q[(w0 + q) * sq + co + d8*8];
    #pragma unroll
    for (int j2 = 0; j2 < 8; ++j2) qr[d8*8 + j2] = bf2f(v[j2]);
  }
  #pragma unroll
  for (int p = 0; p < 4; ++p) {
    const int c = tid + p * 256;
    const int r = c >> 5, cc = (c & 31) << 3;
    *(u16x8*)&Ks[r][cc] = *(const u16x8*)&K[(w0 + r) * sk + cc];
    *(u16x8*)&Vs[r][cc] = *(const u16x8*)&V[(w0 + r) * sv + cc];
  }
  __syncthreads();

  float s[32];
  float mx = -1e30f;
  const float scale = 0.17677669529663687f;   // 1/sqrt(32)
  #pragma unroll
  for (int k = 0; k < 32; ++k) {
    float a = 0.f;
    #pragma unroll
    for (int d8 = 0; d8 < 4; ++d8) {
      u16x8 v = *(const u16x8*)&Ks[k][co + d8*8];
      #pragma unroll
      for (int j2 = 0; j2 < 8; ++j2) a += qr[d8*8 + j2] * bf2f(v[j2]);
    }
    a *= scale;
    s[k] = a;
    mx = fmaxf(mx, a);
  }
  float sum = 0.f;
  #pragma unroll
  for (int k = 0; k < 32; ++k) { float e = __expf(s[k] - mx); s[k] = e; sum += e; }
  const float inv = 1.f / sum;

  float oa[32];
  #pragma unroll
  for (int d = 0; d < 32; ++d) oa[d] = 0.f;
  #pragma unroll
  for (int k = 0; k < 32; ++k) {
    const float p = s[k];
    #pragma unroll
    for (int d8 = 0; d8 < 4; ++d8) {
      u16x8 v = *(const u16x8*)&Vs[k][co + d8*8];
      #pragma unroll
      for (int j2 = 0; j2 < 8; ++j2) oa[d8*8 + j2] += p * bf2f(v[j2]);
    }
  }
  #pragma unroll
  for (int d8 = 0; d8 < 4; ++d8) {
    u16x8 ov;
    #pragma unroll
    for (int j2 = 0; j2 < 8; ++j2) ov[j2] = f2bf(oa[d8*8 + j2] * inv);
    *(u16x8*)&O[(w0 + q) * so + co + d8*8] = ov;
  }
}

// ---------------------------------------------------------------------------
// Fused residual + LayerNorm over D=256. One wave per token row.
// X fp32, R bf16; Y fp32 or bf16. Y may alias X (per-lane read-then-write).
// ---------------------------------------------------------------------------
template<int OUT_BF16>
__global__ __launch_bounds__(256) void ln_resid(
    const float* X, const u16* __restrict__ R,
    const float* __restrict__ g, const float* __restrict__ be,
    void* Y)
{
  const int tid = threadIdx.x;
  const int lane = tid & 63, w = tid >> 6;
  const size_t row = (size_t)blockIdx.x * 4 + w;
  const size_t off = row * 256 + (size_t)(lane << 2);
  f32x4 x = *(const f32x4*)&X[off];
  u16x4 rb = *(const u16x4*)&R[off];
  const float v0 = x[0] + bf2f(rb[0]), v1 = x[1] + bf2f(rb[1]);
  const float v2 = x[2] + bf2f(rb[2]), v3 = x[3] + bf2f(rb[3]);
  float s  = v0 + v1 + v2 + v3;
  float s2 = v0*v0 + v1*v1 + v2*v2 + v3*v3;
  #pragma unroll
  for (int d = 1; d < 64; d <<= 1) {
    s  += __shfl_xor(s,  d, 64);
    s2 += __shfl_xor(s2, d, 64);
  }
  const float m   = s  * (1.f/256.f);
  const float var = s2 * (1.f/256.f) - m*m;
  const float rs  = rsqrtf(var + 1e-5f);
  f32x4 gg = *(const f32x4*)&g[lane << 2];
  f32x4 bb = *(const f32x4*)&be[lane << 2];
  const float y0 = (v0 - m) * rs * gg[0] + bb[0];
  const float y1 = (v1 - m) * rs * gg[1] + bb[1];
  const float y2 = (v2 - m) * rs * gg[2] + bb[2];
  const float y3 = (v3 - m) * rs * gg[3] + bb[3];
  if (OUT_BF16) {
    u16x4 oo = { f2bf(y0), f2bf(y1), f2bf(y2), f2bf(y3) };
    *(u16x4*)((u16*)Y + off) = oo;
  } else {
    f32x4 oo; oo[0] = y0; oo[1] = y1; oo[2] = y2; oo[3] = y3;
    *(f32x4*)((float*)Y + off) = oo;
  }
}

// ---------------------------------------------------------------------------
__global__ __launch_bounds__(256) void wprep(
    const float* __restrict__ W, u16* __restrict__ Wt, int K, int N)
{
  const int idx = blockIdx.x * 256 + threadIdx.x;
  if (idx >= K * N) return;
  const int k = idx / N, n = idx - k * N;
  Wt[(size_t)n * K + k] = f2bf(W[idx]);
}

__global__ __launch_bounds__(256) void bcat(
    const float* __restrict__ a, const float* __restrict__ b,
    const float* __restrict__ c, float* __restrict__ o)
{
  const int i = blockIdx.x * 256 + threadIdx.x;
  o[i] = i < 256 ? a[i] : (i < 512 ? b[i - 256] : c[i - 512]);
}

__global__ __launch_bounds__(256) void f32_to_bf16(
    const float* __restrict__ X, u16* __restrict__ Y)
{
  const size_t i = ((size_t)blockIdx.x * 256 + threadIdx.x) * 8;
  f32x4 a = *(const f32x4*)&X[i];
  f32x4 b = *(const f32x4*)&X[i + 4];
  u16x8 o = { f2bf(a[0]), f2bf(a[1]), f2bf(a[2]), f2bf(a[3]),
              f2bf(b[0]), f2bf(b[1]), f2bf(b[2]), f2bf(b[3]) };
  *(u16x8*)&Y[i] = o;
}

// ---------------------------------------------------------------------------
extern "C" void kernel_launch(void* const* d_in, const int* in_sizes, int n_in,
                              void* d_out, int out_size, void* d_ws, size_t ws_size,
                              hipStream_t stream)
{
  const float* query  = (const float*)d_in[0];
  const float* keyval = (const float*)d_in[1];
  const float* Wq = (const float*)d_in[2];  const float* bq  = (const float*)d_in[3];
  const float* Wk = (const float*)d_in[4];  const float* bk  = (const float*)d_in[5];
  const float* Wv = (const float*)d_in[6];  const float* bv  = (const float*)d_in[7];
  const float* Wo = (const float*)d_in[8];  const float* bo  = (const float*)d_in[9];
  const float* g1 = (const float*)d_in[10]; const float* be1 = (const float*)d_in[11];
  const float* W1 = (const float*)d_in[12]; const float* bf1 = (const float*)d_in[13];
  const float* W2 = (const float*)d_in[14]; const float* bf2 = (const float*)d_in[15];
  const float* g2 = (const float*)d_in[16]; const float* be2 = (const float*)d_in[17];

  const int M = 131072;      // B*L token rows
  char* ws = (char*)d_ws;
  // Workspace (~450 MiB of 512 MiB d_ws; d_out = fp32 pre-LN scratch):
  //   [0,64)     xcur bf16 [M][256]
  //   [64,128)   x1   bf16 [M][256]
  //   [128,192)  kvb  bf16 [M][256]   (layer-1 KV input, pre-converted)
  //   [192,448)  work: L1: Qc [M][256] @192 + KVc [M][512] @256
  //                    L2: QKVc [M][768] @192
  //                    FFN: Hc [M][1024] @192
  //   [448,..)   bf16 weights + fused qkv bias
  u16*  xcur = (u16*)ws;
  u16*  x1   = (u16*)(ws + (64ull  << 20));
  u16*  kvb  = (u16*)(ws + (128ull << 20));
  u16*  Qc   = (u16*)(ws + (192ull << 20));
  u16*  KVc  = (u16*)(ws + (256ull << 20));
  u16*  QKVc = (u16*)(ws + (192ull << 20));
  u16*  Hc   = (u16*)(ws + (192ull << 20));
  u16*  WqkvT = (u16*)(ws + (448ull << 20));   // [768][256]
  u16*  WoT   = WqkvT + 196608;                // [256][256]
  u16*  W1T   = WoT   + 65536;                 // [1024][256]
  u16*  W2T   = W1T   + 262144;                // [256][1024]
  float* bqkv = (float*)(W2T + 262144);        // [768]
  float* tmp  = (float*)d_out;                 // [M][256] fp32

  wprep<<<256,  256, 0, stream>>>(Wq, WqkvT,          256, 256);
  wprep<<<256,  256, 0, stream>>>(Wk, WqkvT +  65536, 256, 256);
  wprep<<<256,  256, 0, stream>>>(Wv, WqkvT + 131072, 256, 256);
  wprep<<<256,  256, 0, stream>>>(Wo, WoT, 256, 256);
  wprep<<<1024, 256, 0, stream>>>(W1, W1T, 256, 1024);
  wprep<<<1024, 256, 0, stream>>>(W2, W2T, 1024, 256);
  bcat<<<3, 256, 0, stream>>>(bq, bk, bv, bqkv);
  f32_to_bf16<<<16384, 256, 0, stream>>>(query,  xcur);
  f32_to_bf16<<<16384, 256, 0, stream>>>(keyval, kvb);

  // NOTE: jnp.roll(x, -16, axis=1) permutes whole windows; the encoder layer is
  // window-local and position-independent, so roll + layer + unroll == layer.
  // Both rolls are elided (bit-exact equivalence).
  auto run_layer = [&](int first, int last) {
    if (first) {   // layer 1: Q from xcur; fused K|V from kvb
      gemm_bt<1,0><<<2048, 256, 0, stream>>>(
          xcur, 256, WqkvT, bqkv, Qc, 256, 256, 2);
      gemm_bt<1,0><<<4096, 256, 0, stream>>>(
          kvb, 256, WqkvT + 65536, bqkv + 256, KVc, 512, 256, 4);
      attn_win<<<4096, 256, 0, stream>>>(Qc, 256, KVc, 512, KVc + 256, 512, Qc, 256);
      gemm_bt<0,0><<<2048, 256, 0, stream>>>(
          Qc, 256, WoT, bo, tmp, 256, 256, 2);
    } else {       // layer 2: fused Q|K|V from xcur
      gemm_bt<1,0><<<6144, 256, 0, stream>>>(
          xcur, 256, WqkvT, bqkv, QKVc, 768, 256, 6);
      attn_win<<<4096, 256, 0, stream>>>(
          QKVc, 768, QKVc + 256, 768, QKVc + 512, 768, QKVc, 768);
      gemm_bt<0,0><<<2048, 256, 0, stream>>>(
          QKVc, 768, WoT, bo, tmp, 256, 256, 2);
    }
    ln_resid<1><<<M/4, 256, 0, stream>>>(tmp, xcur, g1, be1, x1);
    gemm_bt<1,1><<<8192, 256, 0, stream>>>(
        x1, 256, W1T, bf1, Hc, 1024, 256, 8);
    gemm_bt<0,0><<<2048, 256, 0, stream>>>(
        Hc, 1024, W2T, bf2, tmp, 256, 1024, 2);
    if (last) ln_resid<0><<<M/4, 256, 0, stream>>>(tmp, x1, g2, be2, d_out); // in-place
    else      ln_resid<1><<<M/4, 256, 0, stream>>>(tmp, x1, g2, be2, xcur);
  };

  run_layer(1, 0);   // layer 1: q = bf16(query), kv = bf16(keyval)
  run_layer(0, 1);   // layer 2: q = kv = xcur; final LN -> d_out
}

// Round 6
// 1354.349 us; speedup vs baseline: 1.3337x; 1.1862x over previous
//
#include <hip/hip_runtime.h>
#include <cstdint>
#include <cstddef>

typedef unsigned short u16;
typedef __bf16 bf16x8 __attribute__((ext_vector_type(8)));
typedef float f32x4 __attribute__((ext_vector_type(4)));
typedef unsigned short u16x8 __attribute__((ext_vector_type(8)));
typedef unsigned short u16x4 __attribute__((ext_vector_type(4)));

__device__ __forceinline__ u16 f2bf(float f) {
  union { float f; unsigned u; } x; x.f = f;
  unsigned r = x.u + 0x7fffu + ((x.u >> 16) & 1u);   // RNE
  return (u16)(r >> 16);
}
__device__ __forceinline__ float bf2f(u16 u) {
  union { unsigned u; float f; } x; x.u = ((unsigned)u) << 16;
  return x.f;
}
// async global->LDS, 16B/lane; LDS dest = wave-uniform base + lane*16 (linear)
__device__ __forceinline__ void gload16(const void* g, void* l) {
  __builtin_amdgcn_global_load_lds(
      (const __attribute__((address_space(1))) unsigned int*)g,
      (__attribute__((address_space(3))) unsigned int*)l, 16, 0, 0);
}

// ---------------------------------------------------------------------------
// GEMM: C = A[.][K](lda) @ Bt^T + bias. A,Bt bf16; Bt[N][K]. 128x128 tile,
// BK=64, 4 waves (2x2 of 64x64), mfma_f32_16x16x32_bf16.
// LDS rows 128B (8 slots of 16B); T2 both-sides swizzle (pre-swizzled global
// source slot + XOR'd ds_read). 1-D grid, col-fastest + bijective XCD chunk.
// TW=1: store C window-transposed Vt[win][col][tok&31] (for attention's V).
// ---------------------------------------------------------------------------
template<int OUT_BF16, int RELU, int TW>
__global__ __launch_bounds__(256) void gemm_bt(
    const u16* __restrict__ Ap, int lda, const u16* __restrict__ Bt,
    const float* __restrict__ bias, void* __restrict__ Cp,
    int N, int K, int gy)
{
  __shared__ u16 As[128 * 64];
  __shared__ u16 Bs[128 * 64];
  const int tid  = threadIdx.x;
  const int lane = tid & 63, w = tid >> 6;
  const int nwg = gridDim.x, o = blockIdx.x;
  const int lid = (o & 7) * (nwg >> 3) + (o >> 3);   // contiguous lid -> same XCD
  const int by = lid % gy, bx = lid / gy;
  const int row0 = bx * 128, col0 = by * 128;
  const int wr = (w >> 1) * 64, wc = (w & 1) * 64;
  const int fr = lane & 15, fg = lane >> 4;          // fragment row / k-group
  const int srow  = (w << 5) + (lane >> 3);
  const int sslot = (lane & 7) ^ (lane >> 3);

  f32x4 acc[4][4] = {};

  for (int k0 = 0; k0 < K; k0 += 64) {
    #pragma unroll
    for (int h = 0; h < 4; ++h)
      gload16((const char*)Ap + ((size_t)(row0 + srow + h*8) * lda + k0) * 2 + sslot*16,
              &As[((w << 5) + h*8) * 64]);
    #pragma unroll
    for (int h = 0; h < 4; ++h)
      gload16((const char*)Bt + ((size_t)(col0 + srow + h*8) * K + k0) * 2 + sslot*16,
              &Bs[((w << 5) + h*8) * 64]);
    __syncthreads();
    #pragma unroll
    for (int kh = 0; kh < 2; ++kh) {
      bf16x8 af[4], bf[4];
      #pragma unroll
      for (int i = 0; i < 4; ++i) {
        const int r = wr + i*16 + fr;
        af[i] = *(const bf16x8*)&As[r*64 + ((((kh << 2) | fg) ^ (fr & 7)) << 3)];
      }
      #pragma unroll
      for (int j = 0; j < 4; ++j) {
        const int r = wc + j*16 + fr;
        bf[j] = *(const bf16x8*)&Bs[r*64 + ((((kh << 2) | fg) ^ (fr & 7)) << 3)];
      }
      #pragma unroll
      for (int i = 0; i < 4; ++i)
        #pragma unroll
        for (int j = 0; j < 4; ++j)
          acc[i][j] = __builtin_amdgcn_mfma_f32_16x16x32_bf16(af[i], bf[j], acc[i][j], 0, 0, 0);
    }
    __syncthreads();
  }

  // epilogue: D[row=fg*4+t][col=fr] per 16x16 fragment (m89-verified mapping)
  #pragma unroll
  for (int j = 0; j < 4; ++j) {
    const int c  = col0 + wc + j*16 + fr;
    const float bv = bias[c];
    #pragma unroll
    for (int i = 0; i < 4; ++i) {
      if (TW) {
        const int rb = row0 + wr + i*16 + fg*4;       // 4 consecutive tokens
        u16x4 vv;
        #pragma unroll
        for (int t = 0; t < 4; ++t) vv[t] = f2bf(acc[i][j][t] + bv);
        *(u16x4*)&((u16*)Cp)[((size_t)(rb >> 5) * 256 + c) * 32 + (rb & 31)] = vv;
      } else {
        #pragma unroll
        for (int t = 0; t < 4; ++t) {
          const int r = row0 + wr + i*16 + fg*4 + t;
          float v = acc[i][j][t] + bv;
          if (RELU) v = v > 0.f ? v : 0.f;
          if (OUT_BF16) ((u16*)Cp)[(size_t)r * N + c] = f2bf(v);
          else          ((float*)Cp)[(size_t)r * N + c] = v;
        }
      }
    }
  }
}

// ---------------------------------------------------------------------------
// MFMA windowed attention. One wave per window (4 waves/block, no block
// barriers). Per head: S=QK^T via 4 mfma (frags loaded global->reg with the
// verified gemm fragment pattern), softmax in C-layout (in-thread + shfl_xor
// over the 16-lane fr group, normalization deferred), P -> wave-private LDS
// (bf16, stride 40) -> A-frags, O=PV via 4 mfma with B-frags from the
// window-transposed Vt[win][dim][key]. O written natural [tok][256].
// O may alias Q (per head, Q cols read before O cols stored; wave-local rows).
// ---------------------------------------------------------------------------
__global__ __launch_bounds__(256) void attn_mfma(
    const u16* Q, int sq, const u16* __restrict__ K, int sk,
    const u16* __restrict__ Vt, u16* O, int so)
{
  __shared__ u16 P[4][32 * 40];
  const int tid = threadIdx.x, lane = tid & 63, w = tid >> 6;
  const int win = blockIdx.x * 4 + w;
  const size_t q0 = (size_t)win * 32;
  const int fr = lane & 15, fg = lane >> 4;
  u16* Pw = &P[w][0];
  const float scale = 0.17677669529663687f;   // 1/sqrt(32)

  for (int h = 0; h < 8; ++h) {
    const int co = h * 32;
    bf16x8 qa[2], kb[2];
    #pragma unroll
    for (int i = 0; i < 2; ++i)
      qa[i] = *(const bf16x8*)&Q[(q0 + i*16 + fr) * sq + co + fg*8];
    #pragma unroll
    for (int j = 0; j < 2; ++j)
      kb[j] = *(const bf16x8*)&K[(q0 + j*16 + fr) * sk + co + fg*8];
    f32x4 s[2][2] = {};
    #pragma unroll
    for (int i = 0; i < 2; ++i)
      #pragma unroll
      for (int j = 0; j < 2; ++j)
        s[i][j] = __builtin_amdgcn_mfma_f32_16x16x32_bf16(qa[i], kb[j], s[i][j], 0, 0, 0);

    // softmax over keys (cols); row q = i*16 + fg*4 + t, cols {fr, 16+fr}
    float inv[2][4];
    #pragma unroll
    for (int i = 0; i < 2; ++i) {
      #pragma unroll
      for (int t = 0; t < 4; ++t) {
        float a0 = s[i][0][t] * scale, a1 = s[i][1][t] * scale;
        float mx = fmaxf(a0, a1);
        #pragma unroll
        for (int d = 1; d < 16; d <<= 1) mx = fmaxf(mx, __shfl_xor(mx, d, 64));
        const float p0 = __expf(a0 - mx), p1 = __expf(a1 - mx);
        float sm = p0 + p1;
        #pragma unroll
        for (int d = 1; d < 16; d <<= 1) sm += __shfl_xor(sm, d, 64);
        inv[i][t] = 1.f / sm;
        const int q = i*16 + fg*4 + t;
        Pw[q*40 + fr]      = f2bf(p0);
        Pw[q*40 + 16 + fr] = f2bf(p1);
      }
    }

    bf16x8 pa[2], vb[2];
    #pragma unroll
    for (int i = 0; i < 2; ++i)
      pa[i] = *(const bf16x8*)&Pw[(i*16 + fr)*40 + fg*8];
    #pragma unroll
    for (int j = 0; j < 2; ++j)
      vb[j] = *(const bf16x8*)&Vt[(size_t)win*8192 + (co + j*16 + fr)*32 + fg*8];
    f32x4 oacc[2][2] = {};
    #pragma unroll
    for (int i = 0; i < 2; ++i)
      #pragma unroll
      for (int j = 0; j < 2; ++j)
        oacc[i][j] = __builtin_amdgcn_mfma_f32_16x16x32_bf16(pa[i], vb[j], oacc[i][j], 0, 0, 0);

    #pragma unroll
    for (int i = 0; i < 2; ++i)
      #pragma unroll
      for (int j = 0; j < 2; ++j)
        #pragma unroll
        for (int t = 0; t < 4; ++t)
          O[(q0 + i*16 + fg*4 + t) * so + co + j*16 + fr] =
              f2bf(oacc[i][j][t] * inv[i][t]);
  }
}

// ---------------------------------------------------------------------------
// Fused residual + LayerNorm over D=256. One wave per token row.
// X fp32, R bf16; Y fp32 or bf16. Y may alias X (per-lane read-then-write).
// ---------------------------------------------------------------------------
template<int OUT_BF16>
__global__ __launch_bounds__(256) void ln_resid(
    const float* X, const u16* __restrict__ R,
    const float* __restrict__ g, const float* __restrict__ be,
    void* Y)
{
  const int tid = threadIdx.x;
  const int lane = tid & 63, w = tid >> 6;
  const size_t row = (size_t)blockIdx.x * 4 + w;
  const size_t off = row * 256 + (size_t)(lane << 2);
  f32x4 x = *(const f32x4*)&X[off];
  u16x4 rb = *(const u16x4*)&R[off];
  const float v0 = x[0] + bf2f(rb[0]), v1 = x[1] + bf2f(rb[1]);
  const float v2 = x[2] + bf2f(rb[2]), v3 = x[3] + bf2f(rb[3]);
  float s  = v0 + v1 + v2 + v3;
  float s2 = v0*v0 + v1*v1 + v2*v2 + v3*v3;
  #pragma unroll
  for (int d = 1; d < 64; d <<= 1) {
    s  += __shfl_xor(s,  d, 64);
    s2 += __shfl_xor(s2, d, 64);
  }
  const float m   = s  * (1.f/256.f);
  const float var = s2 * (1.f/256.f) - m*m;
  const float rs  = rsqrtf(var + 1e-5f);
  f32x4 gg = *(const f32x4*)&g[lane << 2];
  f32x4 bb = *(const f32x4*)&be[lane << 2];
  const float y0 = (v0 - m) * rs * gg[0] + bb[0];
  const float y1 = (v1 - m) * rs * gg[1] + bb[1];
  const float y2 = (v2 - m) * rs * gg[2] + bb[2];
  const float y3 = (v3 - m) * rs * gg[3] + bb[3];
  if (OUT_BF16) {
    u16x4 oo = { f2bf(y0), f2bf(y1), f2bf(y2), f2bf(y3) };
    *(u16x4*)((u16*)Y + off) = oo;
  } else {
    f32x4 oo; oo[0] = y0; oo[1] = y1; oo[2] = y2; oo[3] = y3;
    *(f32x4*)((float*)Y + off) = oo;
  }
}

// ---------------------------------------------------------------------------
__global__ __launch_bounds__(256) void wprep(
    const float* __restrict__ W, u16* __restrict__ Wt, int K, int N)
{
  const int idx = blockIdx.x * 256 + threadIdx.x;
  if (idx >= K * N) return;
  const int k = idx / N, n = idx - k * N;
  Wt[(size_t)n * K + k] = f2bf(W[idx]);
}

__global__ __launch_bounds__(256) void f32_to_bf16(
    const float* __restrict__ X, u16* __restrict__ Y)
{
  const size_t i = ((size_t)blockIdx.x * 256 + threadIdx.x) * 8;
  f32x4 a = *(const f32x4*)&X[i];
  f32x4 b = *(const f32x4*)&X[i + 4];
  u16x8 o = { f2bf(a[0]), f2bf(a[1]), f2bf(a[2]), f2bf(a[3]),
              f2bf(b[0]), f2bf(b[1]), f2bf(b[2]), f2bf(b[3]) };
  *(u16x8*)&Y[i] = o;
}

// ---------------------------------------------------------------------------
extern "C" void kernel_launch(void* const* d_in, const int* in_sizes, int n_in,
                              void* d_out, int out_size, void* d_ws, size_t ws_size,
                              hipStream_t stream)
{
  const float* query  = (const float*)d_in[0];
  const float* keyval = (const float*)d_in[1];
  const float* Wq = (const float*)d_in[2];  const float* bq  = (const float*)d_in[3];
  const float* Wk = (const float*)d_in[4];  const float* bk  = (const float*)d_in[5];
  const float* Wv = (const float*)d_in[6];  const float* bv  = (const float*)d_in[7];
  const float* Wo = (const float*)d_in[8];  const float* bo  = (const float*)d_in[9];
  const float* g1 = (const float*)d_in[10]; const float* be1 = (const float*)d_in[11];
  const float* W1 = (const float*)d_in[12]; const float* bf1 = (const float*)d_in[13];
  const float* W2 = (const float*)d_in[14]; const float* bf2 = (const float*)d_in[15];
  const float* g2 = (const float*)d_in[16]; const float* be2 = (const float*)d_in[17];

  const int M = 131072;      // B*L token rows
  char* ws = (char*)d_ws;
  // Workspace (~450 MiB of 512 MiB d_ws; d_out = fp32 pre-LN scratch):
  //   [0,64)     xcur bf16 [M][256]
  //   [64,128)   x1   bf16 [M][256]
  //   [128,192)  kvb  bf16 [M][256]
  //   [192,256)  Qc   bf16 [M][256]        (attention O written in place)
  //   [256,320)  Kc   bf16 [M][256]
  //   [320,384)  Vtc  bf16 [4096 win][256][32]   (window-transposed V)
  //   [192,448)  Hc   bf16 [M][1024]       (FFN hidden; reuses Qc/Kc/Vtc)
  //   [448,..)   bf16 weights
  u16*  xcur = (u16*)ws;
  u16*  x1   = (u16*)(ws + (64ull  << 20));
  u16*  kvb  = (u16*)(ws + (128ull << 20));
  u16*  Qc   = (u16*)(ws + (192ull << 20));
  u16*  Kc   = (u16*)(ws + (256ull << 20));
  u16*  Vtc  = (u16*)(ws + (320ull << 20));
  u16*  Hc   = (u16*)(ws + (192ull << 20));
  u16*  WqT  = (u16*)(ws + (448ull << 20));    // [256][256]
  u16*  WkT  = WqT + 65536;
  u16*  WvT  = WkT + 65536;
  u16*  WoT  = WvT + 65536;
  u16*  W1T  = WoT + 65536;    // [1024][256]
  u16*  W2T  = W1T + 262144;   // [256][1024]
  float* tmp = (float*)d_out;  // [M][256] fp32

  wprep<<<256,  256, 0, stream>>>(Wq, WqT, 256, 256);
  wprep<<<256,  256, 0, stream>>>(Wk, WkT, 256, 256);
  wprep<<<256,  256, 0, stream>>>(Wv, WvT, 256, 256);
  wprep<<<256,  256, 0, stream>>>(Wo, WoT, 256, 256);
  wprep<<<1024, 256, 0, stream>>>(W1, W1T, 256, 1024);
  wprep<<<1024, 256, 0, stream>>>(W2, W2T, 1024, 256);
  f32_to_bf16<<<16384, 256, 0, stream>>>(query,  xcur);
  f32_to_bf16<<<16384, 256, 0, stream>>>(keyval, kvb);

  // NOTE: jnp.roll(x, -16, axis=1) permutes whole windows; the encoder layer is
  // window-local and position-independent, so roll + layer + unroll == layer.
  // Both rolls are elided (bit-exact equivalence).
  auto run_layer = [&](const u16* xq, const u16* xkv, int last) {
    gemm_bt<1,0,0><<<2048, 256, 0, stream>>>(xq,  256, WqT, bq, Qc,  256, 256, 2);
    gemm_bt<1,0,0><<<2048, 256, 0, stream>>>(xkv, 256, WkT, bk, Kc,  256, 256, 2);
    gemm_bt<1,0,1><<<2048, 256, 0, stream>>>(xkv, 256, WvT, bv, Vtc, 256, 256, 2);
    attn_mfma<<<1024, 256, 0, stream>>>(Qc, 256, Kc, 256, Vtc, Qc, 256);
    gemm_bt<0,0,0><<<2048, 256, 0, stream>>>(Qc, 256, WoT, bo, tmp, 256, 256, 2);
    ln_resid<1><<<M/4, 256, 0, stream>>>(tmp, xq, g1, be1, x1);
    gemm_bt<1,1,0><<<8192, 256, 0, stream>>>(x1, 256, W1T, bf1, Hc, 1024, 256, 8);
    gemm_bt<0,0,0><<<2048, 256, 0, stream>>>(Hc, 1024, W2T, bf2, tmp, 256, 1024, 2);
    if (last) ln_resid<0><<<M/4, 256, 0, stream>>>(tmp, x1, g2, be2, d_out); // in-place
    else      ln_resid<1><<<M/4, 256, 0, stream>>>(tmp, x1, g2, be2, xcur);
  };

  run_layer(xcur, kvb,  0);   // layer 1: q = bf16(query), kv = bf16(keyval)
  run_layer(xcur, xcur, 1);   // layer 2: q = kv = xcur; final LN -> d_out
}

// Round 7
// 1251.702 us; speedup vs baseline: 1.4430x; 1.0820x over previous
//
#include <hip/hip_runtime.h>
#include <cstdint>
#include <cstddef>

typedef unsigned short u16;
typedef __bf16 bf16x8 __attribute__((ext_vector_type(8)));
typedef float f32x4 __attribute__((ext_vector_type(4)));
typedef unsigned short u16x8 __attribute__((ext_vector_type(8)));
typedef unsigned short u16x4 __attribute__((ext_vector_type(4)));

__device__ __forceinline__ u16 f2bf(float f) {
  union { float f; unsigned u; } x; x.f = f;
  unsigned r = x.u + 0x7fffu + ((x.u >> 16) & 1u);   // RNE
  return (u16)(r >> 16);
}
__device__ __forceinline__ float bf2f(u16 u) {
  union { unsigned u; float f; } x; x.u = ((unsigned)u) << 16;
  return x.f;
}
// async global->LDS, 16B/lane; LDS dest = wave-uniform base + lane*16 (linear)
__device__ __forceinline__ void gload16(const void* g, void* l) {
  __builtin_amdgcn_global_load_lds(
      (const __attribute__((address_space(1))) unsigned int*)g,
      (__attribute__((address_space(3))) unsigned int*)l, 16, 0, 0);
}

// ---------------------------------------------------------------------------
// GEMM: C = A[.][K](lda) @ Bt^T + bias. A,Bt bf16; Bt[N][K]. 128x128 tile,
// BK=64, 4 waves, mfma_f32_16x16x32_bf16. T3 minimal 2-phase: double-buffered
// LDS, next tile's global_load_lds issued BEFORE current tile's compute, ONE
// barrier per K-step (drains stage for next iter). T2 both-sides swizzle:
// pre-swizzled global source slot + XOR'd ds_read (128B rows, 8 slots).
// 1-D grid, col-fastest + bijective XCD chunking (nwg%8==0).
// MODE 0: natural bf16 out C0[r*ldc + coff + c]
// MODE 1: natural bf16 + ReLU
// MODE 2: QKV route (N=768): col<512 natural into C0 (ldc=512);
//         col>=512 window-transposed into C2[win][c-512][tok&31]
// MODE 3: pure window-transposed into C2[win][c][tok&31]
// ---------------------------------------------------------------------------
template<int MODE>
__global__ __launch_bounds__(256) void gemm_bt(
    const u16* __restrict__ Ap, int lda, const u16* __restrict__ Bt,
    const float* __restrict__ bias, u16* __restrict__ C0, int ldc, int coff,
    u16* __restrict__ C2, int N, int K, int gy)
{
  __shared__ u16 As[2][128 * 64];
  __shared__ u16 Bs[2][128 * 64];
  const int tid  = threadIdx.x;
  const int lane = tid & 63, w = tid >> 6;
  const int nwg = gridDim.x, o = blockIdx.x;
  const int lid = (o & 7) * (nwg >> 3) + (o >> 3);   // contiguous lid -> same XCD
  const int by = lid % gy, bx = lid / gy;
  const int row0 = bx * 128, col0 = by * 128;
  const int wr = (w >> 1) * 64, wc = (w & 1) * 64;
  const int fr = lane & 15, fg = lane >> 4;          // fragment row / k-group
  const int srow  = (w << 5) + (lane >> 3);
  const int sslot = (lane & 7) ^ (lane >> 3);

  auto stage = [&](int buf, int k0) {
    #pragma unroll
    for (int h = 0; h < 4; ++h)
      gload16((const char*)Ap + ((size_t)(row0 + srow + h*8) * lda + k0) * 2 + sslot*16,
              &As[buf][((w << 5) + h*8) * 64]);
    #pragma unroll
    for (int h = 0; h < 4; ++h)
      gload16((const char*)Bt + ((size_t)(col0 + srow + h*8) * K + k0) * 2 + sslot*16,
              &Bs[buf][((w << 5) + h*8) * 64]);
  };

  f32x4 acc[4][4] = {};

  stage(0, 0);
  __syncthreads();                  // prologue drain
  int cur = 0;
  for (int k0 = 0; k0 < K; k0 += 64) {
    if (k0 + 64 < K) stage(cur ^ 1, k0 + 64);   // prefetch next (in flight)
    #pragma unroll
    for (int kh = 0; kh < 2; ++kh) {
      bf16x8 af[4], bf[4];
      #pragma unroll
      for (int i = 0; i < 4; ++i) {
        const int r = wr + i*16 + fr;
        af[i] = *(const bf16x8*)&As[cur][r*64 + ((((kh << 2) | fg) ^ (fr & 7)) << 3)];
      }
      #pragma unroll
      for (int j = 0; j < 4; ++j) {
        const int r = wc + j*16 + fr;
        bf[j] = *(const bf16x8*)&Bs[cur][r*64 + ((((kh << 2) | fg) ^ (fr & 7)) << 3)];
      }
      #pragma unroll
      for (int i = 0; i < 4; ++i)
        #pragma unroll
        for (int j = 0; j < 4; ++j)
          acc[i][j] = __builtin_amdgcn_mfma_f32_16x16x32_bf16(af[i], bf[j], acc[i][j], 0, 0, 0);
    }
    __syncthreads();                // all reads done + next stage drained
    cur ^= 1;
  }

  // epilogue: D[row=fg*4+t][col=fr] per 16x16 fragment (m89-verified mapping)
  const int vpart = (MODE == 3) || (MODE == 2 && col0 >= 512);  // wave-uniform
  #pragma unroll
  for (int j = 0; j < 4; ++j) {
    const int c  = col0 + wc + j*16 + fr;
    const float bv = bias[c];
    #pragma unroll
    for (int i = 0; i < 4; ++i) {
      if (vpart) {
        const int cv = (MODE == 2) ? c - 512 : c;
        const int rb = row0 + wr + i*16 + fg*4;   // 4 consecutive tokens
        u16x4 vv;
        #pragma unroll
        for (int t = 0; t < 4; ++t) vv[t] = f2bf(acc[i][j][t] + bv);
        *(u16x4*)&C2[((size_t)(rb >> 5) * 256 + cv) * 32 + (rb & 31)] = vv;
      } else {
        #pragma unroll
        for (int t = 0; t < 4; ++t) {
          const int r = row0 + wr + i*16 + fg*4 + t;
          float v = acc[i][j][t] + bv;
          if (MODE == 1) v = v > 0.f ? v : 0.f;
          C0[(size_t)r * ldc + coff + c] = f2bf(v);
        }
      }
    }
  }
}

// ---------------------------------------------------------------------------
// MFMA windowed attention. One wave per window (4 waves/block, no block
// barriers). Per head: S=QK^T via 4 mfma (frags global->reg, verified gemm
// fragment pattern), softmax in C-layout (shfl_xor over 16-lane fr group,
// normalization deferred), P -> wave-private LDS -> A-frags, O=PV via 4 mfma
// with B-frags from window-transposed Vt[win][dim][key]. O natural [tok][so].
// O may alias Q (per head, Q cols read before O cols stored; wave-local rows).
// ---------------------------------------------------------------------------
__global__ __launch_bounds__(256) void attn_mfma(
    const u16* Q, int sq, const u16* __restrict__ K, int sk,
    const u16* __restrict__ Vt, u16* O, int so)
{
  __shared__ u16 P[4][32 * 40];
  const int tid = threadIdx.x, lane = tid & 63, w = tid >> 6;
  const int win = blockIdx.x * 4 + w;
  const size_t q0 = (size_t)win * 32;
  const int fr = lane & 15, fg = lane >> 4;
  u16* Pw = &P[w][0];
  const float scale = 0.17677669529663687f;   // 1/sqrt(32)

  for (int h = 0; h < 8; ++h) {
    const int co = h * 32;
    bf16x8 qa[2], kb[2];
    #pragma unroll
    for (int i = 0; i < 2; ++i)
      qa[i] = *(const bf16x8*)&Q[(q0 + i*16 + fr) * sq + co + fg*8];
    #pragma unroll
    for (int j = 0; j < 2; ++j)
      kb[j] = *(const bf16x8*)&K[(q0 + j*16 + fr) * sk + co + fg*8];
    f32x4 s[2][2] = {};
    #pragma unroll
    for (int i = 0; i < 2; ++i)
      #pragma unroll
      for (int j = 0; j < 2; ++j)
        s[i][j] = __builtin_amdgcn_mfma_f32_16x16x32_bf16(qa[i], kb[j], s[i][j], 0, 0, 0);

    float inv[2][4];
    #pragma unroll
    for (int i = 0; i < 2; ++i) {
      #pragma unroll
      for (int t = 0; t < 4; ++t) {
        float a0 = s[i][0][t] * scale, a1 = s[i][1][t] * scale;
        float mx = fmaxf(a0, a1);
        #pragma unroll
        for (int d = 1; d < 16; d <<= 1) mx = fmaxf(mx, __shfl_xor(mx, d, 64));
        const float p0 = __expf(a0 - mx), p1 = __expf(a1 - mx);
        float sm = p0 + p1;
        #pragma unroll
        for (int d = 1; d < 16; d <<= 1) sm += __shfl_xor(sm, d, 64);
        inv[i][t] = 1.f / sm;
        const int q = i*16 + fg*4 + t;
        Pw[q*40 + fr]      = f2bf(p0);
        Pw[q*40 + 16 + fr] = f2bf(p1);
      }
    }

    bf16x8 pa[2], vb[2];
    #pragma unroll
    for (int i = 0; i < 2; ++i)
      pa[i] = *(const bf16x8*)&Pw[(i*16 + fr)*40 + fg*8];
    #pragma unroll
    for (int j = 0; j < 2; ++j)
      vb[j] = *(const bf16x8*)&Vt[(size_t)win*8192 + (co + j*16 + fr)*32 + fg*8];
    f32x4 oacc[2][2] = {};
    #pragma unroll
    for (int i = 0; i < 2; ++i)
      #pragma unroll
      for (int j = 0; j < 2; ++j)
        oacc[i][j] = __builtin_amdgcn_mfma_f32_16x16x32_bf16(pa[i], vb[j], oacc[i][j], 0, 0, 0);

    #pragma unroll
    for (int i = 0; i < 2; ++i)
      #pragma unroll
      for (int j = 0; j < 2; ++j)
        #pragma unroll
        for (int t = 0; t < 4; ++t)
          O[(q0 + i*16 + fg*4 + t) * so + co + j*16 + fr] =
              f2bf(oacc[i][j][t] * inv[i][t]);
  }
}

// ---------------------------------------------------------------------------
// Fused residual + LayerNorm over D=256. One wave per token row.
// X bf16, R bf16; Y fp32 or bf16.
// ---------------------------------------------------------------------------
template<int OUT_BF16>
__global__ __launch_bounds__(256) void ln_resid(
    const u16* __restrict__ X, const u16* __restrict__ R,
    const float* __restrict__ g, const float* __restrict__ be,
    void* Y)
{
  const int tid = threadIdx.x;
  const int lane = tid & 63, w = tid >> 6;
  const size_t row = (size_t)blockIdx.x * 4 + w;
  const size_t off = row * 256 + (size_t)(lane << 2);
  u16x4 xb = *(const u16x4*)&X[off];
  u16x4 rb = *(const u16x4*)&R[off];
  const float v0 = bf2f(xb[0]) + bf2f(rb[0]), v1 = bf2f(xb[1]) + bf2f(rb[1]);
  const float v2 = bf2f(xb[2]) + bf2f(rb[2]), v3 = bf2f(xb[3]) + bf2f(rb[3]);
  float s  = v0 + v1 + v2 + v3;
  float s2 = v0*v0 + v1*v1 + v2*v2 + v3*v3;
  #pragma unroll
  for (int d = 1; d < 64; d <<= 1) {
    s  += __shfl_xor(s,  d, 64);
    s2 += __shfl_xor(s2, d, 64);
  }
  const float m   = s  * (1.f/256.f);
  const float var = s2 * (1.f/256.f) - m*m;
  const float rs  = rsqrtf(var + 1e-5f);
  f32x4 gg = *(const f32x4*)&g[lane << 2];
  f32x4 bb = *(const f32x4*)&be[lane << 2];
  const float y0 = (v0 - m) * rs * gg[0] + bb[0];
  const float y1 = (v1 - m) * rs * gg[1] + bb[1];
  const float y2 = (v2 - m) * rs * gg[2] + bb[2];
  const float y3 = (v3 - m) * rs * gg[3] + bb[3];
  if (OUT_BF16) {
    u16x4 oo = { f2bf(y0), f2bf(y1), f2bf(y2), f2bf(y3) };
    *(u16x4*)((u16*)Y + off) = oo;
  } else {
    f32x4 oo; oo[0] = y0; oo[1] = y1; oo[2] = y2; oo[3] = y3;
    *(f32x4*)((float*)Y + off) = oo;
  }
}

// ---------------------------------------------------------------------------
__global__ __launch_bounds__(256) void wprep(
    const float* __restrict__ W, u16* __restrict__ Wt, int K, int N)
{
  const int idx = blockIdx.x * 256 + threadIdx.x;
  if (idx >= K * N) return;
  const int k = idx / N, n = idx - k * N;
  Wt[(size_t)n * K + k] = f2bf(W[idx]);
}

__global__ __launch_bounds__(256) void bcat(
    const float* __restrict__ a, const float* __restrict__ b,
    const float* __restrict__ c, float* __restrict__ o)
{
  const int i = blockIdx.x * 256 + threadIdx.x;
  o[i] = i < 256 ? a[i] : (i < 512 ? b[i - 256] : c[i - 512]);
}

__global__ __launch_bounds__(256) void f32_to_bf16(
    const float* __restrict__ X, u16* __restrict__ Y)
{
  const size_t i = ((size_t)blockIdx.x * 256 + threadIdx.x) * 8;
  f32x4 a = *(const f32x4*)&X[i];
  f32x4 b = *(const f32x4*)&X[i + 4];
  u16x8 o = { f2bf(a[0]), f2bf(a[1]), f2bf(a[2]), f2bf(a[3]),
              f2bf(b[0]), f2bf(b[1]), f2bf(b[2]), f2bf(b[3]) };
  *(u16x8*)&Y[i] = o;
}

// ---------------------------------------------------------------------------
extern "C" void kernel_launch(void* const* d_in, const int* in_sizes, int n_in,
                              void* d_out, int out_size, void* d_ws, size_t ws_size,
                              hipStream_t stream)
{
  const float* query  = (const float*)d_in[0];
  const float* keyval = (const float*)d_in[1];
  const float* Wq = (const float*)d_in[2];  const float* bq  = (const float*)d_in[3];
  const float* Wk = (const float*)d_in[4];  const float* bk  = (const float*)d_in[5];
  const float* Wv = (const float*)d_in[6];  const float* bv  = (const float*)d_in[7];
  const float* Wo = (const float*)d_in[8];  const float* bo  = (const float*)d_in[9];
  const float* g1 = (const float*)d_in[10]; const float* be1 = (const float*)d_in[11];
  const float* W1 = (const float*)d_in[12]; const float* bf1 = (const float*)d_in[13];
  const float* W2 = (const float*)d_in[14]; const float* bf2 = (const float*)d_in[15];
  const float* g2 = (const float*)d_in[16]; const float* be2 = (const float*)d_in[17];

  const int M  = 131072;     // B*L token rows
  const int MH = 65536;      // FFN row chunk (2 chunks)
  char* ws = (char*)d_ws;
  // Workspace (<=450 MiB of 512 MiB d_ws):
  //   [0,64)     xcur bf16 [M][256]
  //   [64,128)   x1   bf16 [M][256]
  //   [128,192)  kvb  bf16 [M][256]
  //   [192,256)  tmp  bf16 [M][256]   (pre-LN GEMM outputs)
  //   [256,384)  QKc  bf16 [M][512]   (Q cols 0-255 | K cols 256-511; attn O
  //                                    written in place over the Q columns)
  //              Hc   bf16 [MH][1024] (FFN hidden, reuses QKc region)
  //   [384,448)  Vtc  bf16 [4096 win][256][32]  (window-transposed V)
  //   [448,..)   bf16 weights + fused qkv bias
  u16*  xcur = (u16*)ws;
  u16*  x1   = (u16*)(ws + (64ull  << 20));
  u16*  kvb  = (u16*)(ws + (128ull << 20));
  u16*  tmp  = (u16*)(ws + (192ull << 20));
  u16*  QKc  = (u16*)(ws + (256ull << 20));
  u16*  Hc   = (u16*)(ws + (256ull << 20));
  u16*  Vtc  = (u16*)(ws + (384ull << 20));
  u16*  WqkvT = (u16*)(ws + (448ull << 20));   // [768][256] = Wq|Wk|Wv rows
  u16*  WoT   = WqkvT + 196608;                // [256][256]
  u16*  W1T   = WoT   + 65536;                 // [1024][256]
  u16*  W2T   = W1T   + 262144;                // [256][1024]
  float* bqkv = (float*)(W2T + 262144);        // [768]

  wprep<<<256,  256, 0, stream>>>(Wq, WqkvT,          256, 256);
  wprep<<<256,  256, 0, stream>>>(Wk, WqkvT +  65536, 256, 256);
  wprep<<<256,  256, 0, stream>>>(Wv, WqkvT + 131072, 256, 256);
  wprep<<<256,  256, 0, stream>>>(Wo, WoT, 256, 256);
  wprep<<<1024, 256, 0, stream>>>(W1, W1T, 256, 1024);
  wprep<<<1024, 256, 0, stream>>>(W2, W2T, 1024, 256);
  bcat<<<3, 256, 0, stream>>>(bq, bk, bv, bqkv);
  f32_to_bf16<<<16384, 256, 0, stream>>>(query,  xcur);
  f32_to_bf16<<<16384, 256, 0, stream>>>(keyval, kvb);

  // NOTE: jnp.roll(x, -16, axis=1) permutes whole windows; the encoder layer is
  // window-local and position-independent, so roll + layer + unroll == layer.
  // Both rolls are elided (bit-exact equivalence).
  auto run_layer = [&](int first, int last) {
    if (first) {   // layer 1: Q from xcur; K,V from kvb (different A matrices)
      gemm_bt<0><<<2048, 256, 0, stream>>>(
          xcur, 256, WqkvT, bq, QKc, 512, 0, nullptr, 256, 256, 2);
      gemm_bt<0><<<2048, 256, 0, stream>>>(
          kvb, 256, WqkvT + 65536, bk, QKc, 512, 256, nullptr, 256, 256, 2);
      gemm_bt<3><<<2048, 256, 0, stream>>>(
          kvb, 256, WqkvT + 131072, bv, nullptr, 0, 0, Vtc, 256, 256, 2);
    } else {       // layer 2: fused Q|K|V from xcur, routed epilogue
      gemm_bt<2><<<6144, 256, 0, stream>>>(
          xcur, 256, WqkvT, bqkv, QKc, 512, 0, Vtc, 768, 256, 6);
    }
    attn_mfma<<<1024, 256, 0, stream>>>(QKc, 512, QKc + 256, 512, Vtc, QKc, 512);
    gemm_bt<0><<<2048, 256, 0, stream>>>(
        QKc, 512, WoT, bo, tmp, 256, 0, nullptr, 256, 256, 2);
    ln_resid<1><<<M/4, 256, 0, stream>>>(tmp, xcur, g1, be1, x1);
    for (int c = 0; c < 2; ++c) {
      const size_t ro = (size_t)c * MH;
      gemm_bt<1><<<4096, 256, 0, stream>>>(
          x1 + ro * 256, 256, W1T, bf1, Hc, 1024, 0, nullptr, 1024, 256, 8);
      gemm_bt<0><<<1024, 256, 0, stream>>>(
          Hc, 1024, W2T, bf2, tmp + ro * 256, 256, 0, nullptr, 256, 1024, 2);
    }
    if (last) ln_resid<0><<<M/4, 256, 0, stream>>>(tmp, x1, g2, be2, d_out);
    else      ln_resid<1><<<M/4, 256, 0, stream>>>(tmp, x1, g2, be2, xcur);
  };

  run_layer(1, 0);   // layer 1: q = bf16(query), kv = bf16(keyval)
  run_layer(0, 1);   // layer 2: q = kv = xcur; final LN -> d_out fp32
}